// Round 1
// 137.263 us; speedup vs baseline: 1.1074x; 1.1074x over previous
//
#include <hip/hip_runtime.h>

typedef __bf16 v8bf __attribute__((ext_vector_type(8)));
typedef __bf16 v4bf __attribute__((ext_vector_type(4)));
typedef __bf16 v2bf __attribute__((ext_vector_type(2)));
typedef float  v4f  __attribute__((ext_vector_type(4)));

namespace {

constexpr int kB = 512, kM = 4096, kH = 8;

// ws layout (bytes): wq 32KB @ 0, wk 32KB @ 32768, wfc 64KB @ 65536
// Tile swizzle: element (r, c) of a row-major [R x C] matrix lives at
//   tile = (r>>4)*(C/32) + (c>>5);  addr = tile*512 + (r&15)*32 + (c&31)

// ---------------- K0: weight casts + swizzle (1/64 folded into Wq) ----------------
__global__ __launch_bounds__(256) void k0_weights(
    const float* __restrict__ Wq, const float* __restrict__ Wk,
    const float* __restrict__ Wfc,
    __bf16* __restrict__ wq, __bf16* __restrict__ wk, __bf16* __restrict__ wfc) {
  int i = blockIdx.x * 256 + threadIdx.x;
  if (i < 16384) {
    int e = i >> 6, k = i & 63;
    int dst = ((e >> 4) * 2 + (k >> 5)) * 512 + (e & 15) * 32 + (k & 31);
    wq[dst] = (__bf16)(Wq[i] * 0.015625f);
  } else if (i < 32768) {
    int j = i - 16384;
    int e = j >> 6, k = j & 63;
    int dst = ((e >> 4) * 2 + (k >> 5)) * 512 + (e & 15) * 32 + (k & 31);
    wk[dst] = (__bf16)Wk[j];
  } else {
    int j = i - 32768;
    int o = j >> 9, f = j & 511;
    int dst = ((o >> 4) * 16 + (f >> 5)) * 512 + (o & 15) * 32 + (f & 31);
    wfc[dst] = (__bf16)Wfc[j];
  }
}

// ---------------- K1: fused per-b mega kernel ----------------
// LN -> per-head {qGEMM, gather, kGEMM, conv, scores, softmax, PV} -> fc (reg acc).
// LDS 53,264 B -> 3 blocks/CU by LDS; grid 512 -> 2/CU resident.
__global__ __launch_bounds__(256, 2) void k_fused(
    const float* __restrict__ feat, const int* __restrict__ sidx,
    const float* __restrict__ gamma, const float* __restrict__ beta,
    const __bf16* __restrict__ wq, const __bf16* __restrict__ wk,
    const float* __restrict__ Wv1, const float* __restrict__ Wv2,
    const __bf16* __restrict__ wfc, float* __restrict__ out) {
  __shared__ __align__(16) __bf16 smem[26624];
  __shared__ float red[4];
  __bf16* s_feat = smem;           // 4096   raw features bf16 (gather source, all heads)
  __bf16* s_qin  = smem + 4096;    // 4096   LN output, tile-swizzled (all heads)
  __bf16* s_kf   = smem + 8192;    // 64x72  gathered kf; aliased as scores later
  __bf16* s_q    = smem + 12800;   // 64x40  (wave-private rows)
  __bf16* s_K    = smem + 15360;   // 64x40
  __bf16* s_vT   = smem + 17920;   // 64x72  v^T [s][n]
  __bf16* s_o    = smem + 22528;   // 4x1024 per-wave o tiles (wave-private)
  __bf16* s_sc   = s_kf;           // alias: s_kf dead once scores start

  const int b = blockIdx.x;
  const int t = threadIdx.x, w = t >> 6, lane = t & 63;
  const int quad = lane >> 4, l16 = lane & 15;

  // ---- LN phase (+ prefetch head-0 gather indices) ----
  const float4* frow4 = reinterpret_cast<const float4*>(feat + (size_t)b * kM);
  const float4* g4  = reinterpret_cast<const float4*>(gamma);
  const float4* be4 = reinterpret_cast<const float4*>(beta);
  float4 xs[4];
  float s = 0.f;
#pragma unroll
  for (int j = 0; j < 4; ++j) {
    xs[j] = frow4[t + j * 256];
    s += xs[j].x + xs[j].y + xs[j].z + xs[j].w;
  }
  int idxr[16], idxn[16];
#pragma unroll
  for (int j = 0; j < 16; ++j) idxr[j] = sidx[t + j * 256];
#pragma unroll
  for (int o = 32; o > 0; o >>= 1) s += __shfl_xor(s, o);
  if (lane == 0) red[w] = s;
  __syncthreads();
  const float mu = (red[0] + red[1] + red[2] + red[3]) * (1.f / kM);
  float var_p = 0.f;
#pragma unroll
  for (int j = 0; j < 4; ++j) {
    float d0 = xs[j].x - mu, d1 = xs[j].y - mu, d2 = xs[j].z - mu, d3 = xs[j].w - mu;
    var_p += d0 * d0 + d1 * d1 + d2 * d2 + d3 * d3;
  }
#pragma unroll
  for (int o = 32; o > 0; o >>= 1) var_p += __shfl_xor(var_p, o);
  __syncthreads();
  if (lane == 0) red[w] = var_p;
  __syncthreads();
  const float var  = (red[0] + red[1] + red[2] + red[3]) * (1.f / kM);
  const float rstd = rsqrtf(var + 1e-5f);
#pragma unroll
  for (int j = 0; j < 4; ++j) {
    const int i4 = t + j * 256;
    float4 g = g4[i4], bt = be4[i4];
    v4bf fb, qb;
    fb[0] = (__bf16)xs[j].x; fb[1] = (__bf16)xs[j].y;
    fb[2] = (__bf16)xs[j].z; fb[3] = (__bf16)xs[j].w;
    qb[0] = (__bf16)((xs[j].x - mu) * rstd * g.x + bt.x);
    qb[1] = (__bf16)((xs[j].y - mu) * rstd * g.y + bt.y);
    qb[2] = (__bf16)((xs[j].z - mu) * rstd * g.z + bt.z);
    qb[3] = (__bf16)((xs[j].w - mu) * rstd * g.w + bt.w);
    *(v4bf*)(s_feat + 4 * i4) = fb;
    // element m = 4*i4 + c -> n = (t>>4) + 16j, k = 4*(t&15) + c
    const int n = (t >> 4) + 16 * j, k = 4 * (t & 15);
    const int dst = ((n >> 4) * 2 + (k >> 5)) * 512 + (n & 15) * 32 + (k & 31);
    *(v4bf*)(s_qin + dst) = qb;
  }
  if (t < 64) { v8bf z = {}; *(v8bf*)(s_kf + t * 72 + 64) = z; }  // conv pad, survives all heads
  __syncthreads();  // bar0: s_feat, s_qin ready

  v4f acc[4] = {{0.f, 0.f, 0.f, 0.f}, {0.f, 0.f, 0.f, 0.f},
                {0.f, 0.f, 0.f, 0.f}, {0.f, 0.f, 0.f, 0.f}};  // fc accumulator

  for (int h = 0; h < kH; ++h) {
    // ---- q-GEMM (s_qin LDS + wq global; s_q rows are wave-private)
    {
      v4f dq0 = {0.f, 0.f, 0.f, 0.f}, dq1 = {0.f, 0.f, 0.f, 0.f};
#pragma unroll
      for (int kt = 0; kt < 2; ++kt) {
        v8bf a  = *(const v8bf*)(s_qin + (2 * w + kt) * 512 + l16 * 32 + 8 * quad);
        v8bf b0 = *(const v8bf*)(wq + (size_t)(4 * h + kt) * 512 + l16 * 32 + 8 * quad);
        v8bf b1 = *(const v8bf*)(wq + (size_t)(4 * h + 2 + kt) * 512 + l16 * 32 + 8 * quad);
        dq0 = __builtin_amdgcn_mfma_f32_16x16x32_bf16(a, b0, dq0, 0, 0, 0);
        dq1 = __builtin_amdgcn_mfma_f32_16x16x32_bf16(a, b1, dq1, 0, 0, 0);
      }
#pragma unroll
      for (int r = 0; r < 4; ++r) {
        s_q[(16 * w + 4 * quad + r) * 40 + l16]      = (__bf16)dq0[r];
        s_q[(16 * w + 4 * quad + r) * 40 + 16 + l16] = (__bf16)dq1[r];
      }
    }

    // ---- prefetch next head's gather indices (overlaps everything below)
    if (h < kH - 1) {
      const int* idxp = sidx + (h + 1) * kM;
#pragma unroll
      for (int j = 0; j < 16; ++j) idxn[j] = idxp[t + j * 256];
    }

    // ---- gather kf from LDS (random b16 reads on the crossbar)
#pragma unroll
    for (int j = 0; j < 16; ++j) {
      int i = t + j * 256;
      s_kf[(i >> 6) * 72 + (i & 63)] = s_feat[idxr[j]];
    }
    __syncthreads();  // bar1: s_kf ready

    // ---- K-GEMM
    {
      v4f dk0 = {0.f, 0.f, 0.f, 0.f}, dk1 = {0.f, 0.f, 0.f, 0.f};
#pragma unroll
      for (int kt = 0; kt < 2; ++kt) {
        v8bf a  = *(const v8bf*)(s_kf + (16 * w + l16) * 72 + 32 * kt + 8 * quad);
        v8bf b0 = *(const v8bf*)(wk + (size_t)(4 * h + kt) * 512 + l16 * 32 + 8 * quad);
        v8bf b1 = *(const v8bf*)(wk + (size_t)(4 * h + 2 + kt) * 512 + l16 * 32 + 8 * quad);
        dk0 = __builtin_amdgcn_mfma_f32_16x16x32_bf16(a, b0, dk0, 0, 0, 0);
        dk1 = __builtin_amdgcn_mfma_f32_16x16x32_bf16(a, b1, dk1, 0, 0, 0);
      }
#pragma unroll
      for (int r = 0; r < 4; ++r) {
        s_K[(16 * w + 4 * quad + r) * 40 + l16]      = (__bf16)dk0[r];
        s_K[(16 * w + 4 * quad + r) * 40 + 16 + l16] = (__bf16)dk1[r];
      }
    }

    // ---- windowed conv + relu + residual, written transposed (v^T[s][n])
    {
      const int n = t & 63, p0 = (t >> 6) * 16;
      float w1[4][3], w2[4];
#pragma unroll
      for (int d = 0; d < 4; ++d) {
#pragma unroll
        for (int c = 0; c < 3; ++c) w1[d][c] = Wv1[(h * 4 + d) * 3 + c];
        w2[d] = Wv2[h * 4 + d];
      }
      v8bf xa = *(const v8bf*)(s_kf + n * 72 + p0);
      v8bf xb = *(const v8bf*)(s_kf + n * 72 + p0 + 8);
      v2bf xc = *(const v2bf*)(s_kf + n * 72 + p0 + 16);  // pad cols zeroed
      float x[18];
#pragma unroll
      for (int c = 0; c < 8; ++c) { x[c] = (float)xa[c]; x[c + 8] = (float)xb[c]; }
      x[16] = (float)xc[0]; x[17] = (float)xc[1];
#pragma unroll
      for (int pp = 0; pp < 16; ++pp) {
        float a0 = x[pp];
#pragma unroll
        for (int d = 0; d < 4; ++d) {
          float v1 = fmaf(x[pp + 2], w1[d][2], fmaf(x[pp + 1], w1[d][1], x[pp] * w1[d][0]));
          a0 = fmaf(fmaxf(v1, 0.f), w2[d], a0);
        }
        s_vT[(p0 + pp) * 72 + n] = (__bf16)a0;
      }
    }
    __syncthreads();  // bar2: s_q, s_K, s_vT ready; all s_kf readers done (s_sc alias safe)

    // ---- scores[qi][n] = q[qi][d] * K[n][d]
    {
      v4f ds[4] = {{0.f, 0.f, 0.f, 0.f}, {0.f, 0.f, 0.f, 0.f},
                   {0.f, 0.f, 0.f, 0.f}, {0.f, 0.f, 0.f, 0.f}};
      v8bf a = *(const v8bf*)(s_q + (16 * w + l16) * 40 + 8 * quad);
#pragma unroll
      for (int nt = 0; nt < 4; ++nt) {
        v8bf bb = *(const v8bf*)(s_K + (16 * nt + l16) * 40 + 8 * quad);
        ds[nt] = __builtin_amdgcn_mfma_f32_16x16x32_bf16(a, bb, ds[nt], 0, 0, 0);
      }
#pragma unroll
      for (int nt = 0; nt < 4; ++nt)
#pragma unroll
        for (int r = 0; r < 4; ++r)
          s_sc[(16 * w + 4 * quad + r) * 72 + 16 * nt + l16] = (__bf16)ds[nt][r];
    }
    // no barrier: wave w owns rows 16w..16w+15 of s_sc end-to-end

    // ---- softmax + attn output
    float* attn_out = out + (size_t)kB * kM + ((size_t)(b * kH + h)) * 4096;
#pragma unroll
    for (int rr = 0; rr < 4; ++rr) {
      const int row = 16 * w + 4 * rr + quad;
      v4bf pv = *(const v4bf*)(s_sc + row * 72 + 4 * l16);
      float e0 = (float)pv[0], e1 = (float)pv[1], e2 = (float)pv[2], e3 = (float)pv[3];
      float mx = fmaxf(fmaxf(e0, e1), fmaxf(e2, e3));
#pragma unroll
      for (int mk = 8; mk > 0; mk >>= 1) mx = fmaxf(mx, __shfl_xor(mx, mk));
      e0 = __expf(e0 - mx); e1 = __expf(e1 - mx);
      e2 = __expf(e2 - mx); e3 = __expf(e3 - mx);
      float ssum = e0 + e1 + e2 + e3;
#pragma unroll
      for (int mk = 8; mk > 0; mk >>= 1) ssum += __shfl_xor(ssum, mk);
      const float inv = 1.0f / ssum;
      e0 *= inv; e1 *= inv; e2 *= inv; e3 *= inv;
      *(float4*)(attn_out + row * 64 + 4 * l16) = make_float4(e0, e1, e2, e3);
      v4bf st;
      st[0] = (__bf16)e0; st[1] = (__bf16)e1; st[2] = (__bf16)e2; st[3] = (__bf16)e3;
      *(v4bf*)(s_sc + row * 72 + 4 * l16) = st;
    }

    // ---- PV: o[qi][s] = attn[qi][n] * vT[s][n]
    v4f dO[4] = {{0.f, 0.f, 0.f, 0.f}, {0.f, 0.f, 0.f, 0.f},
                 {0.f, 0.f, 0.f, 0.f}, {0.f, 0.f, 0.f, 0.f}};
#pragma unroll
    for (int kt = 0; kt < 2; ++kt) {
      v8bf a = *(const v8bf*)(s_sc + (16 * w + l16) * 72 + 32 * kt + 8 * quad);
#pragma unroll
      for (int st = 0; st < 4; ++st) {
        v8bf bb = *(const v8bf*)(s_vT + (16 * st + l16) * 72 + 32 * kt + 8 * quad);
        dO[st] = __builtin_amdgcn_mfma_f32_16x16x32_bf16(a, bb, dO[st], 0, 0, 0);
      }
    }

    // ---- fc partial: acc[n][o] += o_h[n][k] * Wfc[o][h*64+k]
    // o round-trips through a wave-private LDS tile to become an A-fragment.
    {
      __bf16* ob = s_o + w * 1024;
#pragma unroll
      for (int st = 0; st < 4; ++st)
#pragma unroll
        for (int r = 0; r < 4; ++r)
          ob[(st >> 1) * 512 + (4 * quad + r) * 32 + (st & 1) * 16 + l16] = (__bf16)dO[st][r];
#pragma unroll
      for (int kt = 0; kt < 2; ++kt) {
        v8bf a = *(const v8bf*)(ob + kt * 512 + l16 * 32 + 8 * quad);
#pragma unroll
        for (int nt = 0; nt < 4; ++nt) {
          v8bf bb = *(const v8bf*)(wfc + (size_t)(nt * 16 + h * 2 + kt) * 512 + l16 * 32 + 8 * quad);
          acc[nt] = __builtin_amdgcn_mfma_f32_16x16x32_bf16(a, bb, acc[nt], 0, 0, 0);
        }
      }
    }
    __syncthreads();  // bar3: all cross-wave reads of s_K/s_vT/s_kf done before next head's writes

    if (h < kH - 1) {
#pragma unroll
      for (int j = 0; j < 16; ++j) idxr[j] = idxn[j];
    }
  }

  // ---- final out write: out[b*4096 + n*64 + o]
  float* orow = out + (size_t)b * kM;
#pragma unroll
  for (int nt = 0; nt < 4; ++nt)
#pragma unroll
    for (int r = 0; r < 4; ++r)
      orow[(16 * w + 4 * quad + r) * 64 + 16 * nt + l16] = acc[nt][r];
}

}  // namespace

extern "C" void kernel_launch(void* const* d_in, const int* in_sizes, int n_in,
                              void* d_out, int out_size, void* d_ws, size_t ws_size,
                              hipStream_t stream) {
  (void)in_sizes; (void)n_in; (void)out_size; (void)ws_size;
  const float* features = (const float*)d_in[0];
  const int*   sidx     = (const int*)d_in[1];
  const float* gamma    = (const float*)d_in[2];
  const float* beta     = (const float*)d_in[3];
  const float* Wq       = (const float*)d_in[4];
  const float* Wk       = (const float*)d_in[5];
  const float* Wv1      = (const float*)d_in[6];
  const float* Wv2      = (const float*)d_in[7];
  const float* Wfc      = (const float*)d_in[8];
  float* out = (float*)d_out;

  char* ws = (char*)d_ws;
  __bf16* ws_wq  = (__bf16*)(ws);
  __bf16* ws_wk  = (__bf16*)(ws + 32768);
  __bf16* ws_wfc = (__bf16*)(ws + 65536);

  hipLaunchKernelGGL(k0_weights, dim3(256), dim3(256), 0, stream,
                     Wq, Wk, Wfc, ws_wq, ws_wk, ws_wfc);
  hipLaunchKernelGGL(k_fused, dim3(kB), dim3(256), 0, stream,
                     features, sidx, gamma, beta, ws_wq, ws_wk, Wv1, Wv2, ws_wfc, out);
}